// Round 5
// baseline (318.785 us; speedup 1.0000x reference)
//
#include <hip/hip_runtime.h>

#define TT 512

typedef _Float16 half4 __attribute__((ext_vector_type(4)));
typedef __attribute__((ext_vector_type(4))) float floatx4;

// raw workgroup barrier (no vmcnt/lgkmcnt drain); LDS FIFO is in-order per CU,
// validated R6-R12 (reads issued pre-barrier stay bit-exact vs post-barrier
// overwrites across 512 steps).
#define BAR() do { __asm__ volatile("" ::: "memory"); \
                   __builtin_amdgcn_s_barrier();      \
                   __asm__ volatile("" ::: "memory"); } while (0)

__device__ __forceinline__ float fast_tanh(float z) {
    const float e = __expf(2.f * z);
    return 1.f - __fdividef(2.f, e + 1.f);
}
__device__ __forceinline__ float f4e(const float4& v, int r) {
    return (r == 0) ? v.x : (r == 1) ? v.y : (r == 2) ? v.z : v.w;
}
__device__ __forceinline__ unsigned pk16(float a, float b) {
    const unsigned ua = __builtin_bit_cast(unsigned short, (_Float16)a);
    const unsigned ub = __builtin_bit_cast(unsigned short, (_Float16)b);
    return ua | (ub << 16);
}

// R5 = R10 8-wave grid + R2/R3-verified register D->B identity + conflict-free
// uint2 LDS + split accumulator chains. (R4 with the __exp2f compile fix:
// fast_tanh reverted to the session-validated __expf form.)
// 128 blocks x 8 waves, 16 batch cols/block. Waves 0-3: L0 M-tile wq at step i.
// Waves 4-7: L1 M-tile wq at step i-2 (h0 prefetched lag-2, off critical path).
// K=64 recurrence = 4 accumulating K=16 MFMAs split into two 2-deep chains;
// the OWN K-fragment (= own tanh'd/packed D tile, layout identity verified R2)
// never touches LDS. Partner fragments cross LDS lag-1 (uint2 layout: quarter-
// wave spans all 32 banks -> 0 conflicts, verified R3 counters).
// One raw 8-wave barrier per interval, as R10.
__global__ void __launch_bounds__(512, 1)
rnn2_r5(const float* __restrict__ x,
        const float* __restrict__ W_ih0, const float* __restrict__ W_hh0,
        const float* __restrict__ b_ih0, const float* __restrict__ b_hh0,
        const float* __restrict__ W_ih1, const float* __restrict__ W_hh1,
        const float* __restrict__ b_ih1, const float* __restrict__ b_hh1,
        const float* __restrict__ W_fc, const float* __restrict__ b_fc,
        float* __restrict__ out)
{
    __shared__ uint2 h0buf[2][256];   // [parity][(4*tile+g)*16 + n]
    __shared__ uint2 h1buf[2][256];
    __shared__ float red[4][16];

    const int tid  = threadIdx.x;
    const int lane = tid & 63;
    const int w    = tid >> 6;      // 0..7
    const int wq   = w & 3;         // M-tile
    const bool isL0 = (w < 4);
    const int g    = lane >> 4;
    const int n    = lane & 15;
    const int b0   = blockIdx.x * 16;

    // zero-init both parities of both buffers (512 uint2 each, 512 threads)
    {
        uint2 z; z.x = 0u; z.y = 0u;
        ((uint2*)h0buf)[tid] = z;
        ((uint2*)h1buf)[tid] = z;
    }

    const int k1 = (wq + 1) & 3, k2 = (wq + 2) & 3, k3 = (wq + 3) & 3;
    const int riA = (4 * k1 + g) * 16 + n;
    const int riB = (4 * k2 + g) * 16 + n;
    const int riC = (4 * k3 + g) * 16 + n;
    const int wi  = (4 * wq + g) * 16 + n;
    const int p0 = g * 16 + n, p1 = (4 + g) * 16 + n,
              p2 = (8 + g) * 16 + n, p3 = (12 + g) * 16 + n;

    const floatx4 zero4 = {0.f, 0.f, 0.f, 0.f};

    auto mk4 = [&](const float* p, half4& h) {
#pragma unroll
        for (int j = 0; j < 4; ++j) h[j] = (_Float16)p[j];
    };

    // weights (single fp16 RTNE)
    half4 wA[4], wB[4];
    float4 wv = {0, 0, 0, 0}, bsv = {0, 0, 0, 0}, wfc = {0, 0, 0, 0};
    if (isL0) {
#pragma unroll
        for (int s = 0; s < 4; ++s) {            // rotated: s=0 is OWN fragment
            const int kt = (wq + s) & 3;
            mk4(W_hh0 + (16 * wq + n) * 64 + 16 * kt + 4 * g, wA[s]);
        }
        wv = *(const float4*)(W_ih0 + 16 * wq + 4 * g);
        const float4 a = *(const float4*)(b_ih0 + 16 * wq + 4 * g);
        const float4 c = *(const float4*)(b_hh0 + 16 * wq + 4 * g);
        bsv = make_float4(a.x + c.x, a.y + c.y, a.z + c.z, a.w + c.w);
    } else {
#pragma unroll
        for (int kt = 0; kt < 4; ++kt)           // absolute: feeds bp[kt]
            mk4(W_ih1 + (16 * wq + n) * 64 + 16 * kt + 4 * g, wA[kt]);
#pragma unroll
        for (int s = 0; s < 4; ++s) {            // rotated: s=0 is OWN fragment
            const int kt = (wq + s) & 3;
            mk4(W_hh1 + (16 * wq + n) * 64 + 16 * kt + 4 * g, wB[s]);
        }
        const float4 a = *(const float4*)(b_ih1 + 16 * wq + 4 * g);
        const float4 c = *(const float4*)(b_hh1 + 16 * wq + 4 * g);
        bsv = make_float4(a.x + c.x, a.y + c.y, a.z + c.z, a.w + c.w);
        wfc = *(const float4*)(W_fc + 16 * wq + 4 * g);
    }

    // register state: own fragment of h (L0: h0, L1: h1); h(-1) = 0
    const uint2 z2 = {0u, 0u};
    half4 st = __builtin_bit_cast(half4, z2);
    half4 bp[4];                                  // L1: h0(i-2) fragments
#pragma unroll
    for (int kt = 0; kt < 4; ++kt) bp[kt] = __builtin_bit_cast(half4, z2);

    const float* xp = x + (long)(b0 + n) * TT;
    float xv = 0.f, xn = 0.f;
    if (isL0) { xv = xp[0]; xn = xp[1]; }

    // ---- L0 interval i: partner reads (lag-1, exposed) + own reg fragment;
    //      two 2-deep MFMA chains; tanh -> pack -> D==next B fragment ----
    auto stepL0 = [&](int i) {
        const int P = i & 1, R = P ^ 1;
        const uint2 qa = h0buf[R][riA];
        const uint2 qb = h0buf[R][riB];
        const uint2 qc = h0buf[R][riC];
        floatx4 a = {__builtin_fmaf(xv, wv.x, bsv.x), __builtin_fmaf(xv, wv.y, bsv.y),
                     __builtin_fmaf(xv, wv.z, bsv.z), __builtin_fmaf(xv, wv.w, bsv.w)};
        a = __builtin_amdgcn_mfma_f32_16x16x16f16(wA[0], st, a, 0, 0, 0);   // own: no wait
        floatx4 b = __builtin_amdgcn_mfma_f32_16x16x16f16(wA[2], __builtin_bit_cast(half4, qb), zero4, 0, 0, 0);
        a = __builtin_amdgcn_mfma_f32_16x16x16f16(wA[1], __builtin_bit_cast(half4, qa), a, 0, 0, 0);
        b = __builtin_amdgcn_mfma_f32_16x16x16f16(wA[3], __builtin_bit_cast(half4, qc), b, 0, 0, 0);
        xv = xn; xn = xp[(i + 2) & (TT - 1)];
        uint2 u;
        u.x = pk16(fast_tanh(a[0] + b[0]), fast_tanh(a[1] + b[1]));
        u.y = pk16(fast_tanh(a[2] + b[2]), fast_tanh(a[3] + b[3]));
        h0buf[P][wi] = u;
        st = __builtin_bit_cast(half4, u);        // D tile == next B fragment
    };

    // ---- L1 interval i (computes h1(i-2)): h1 partner reads lag-1 (exposed),
    //      ih MFMAs on prefetched regs (no wait), h0(i-1) prefetch off-path ----
    auto stepL1 = [&](int i, bool last) {
        const int P = i & 1, R = P ^ 1;
        const uint2 ca = h1buf[R][riA];
        const uint2 cb = h1buf[R][riB];
        const uint2 cc = h1buf[R][riC];
        const uint2 na = h0buf[R][p0];
        const uint2 nb = h0buf[R][p1];
        const uint2 nc = h0buf[R][p2];
        const uint2 nd = h0buf[R][p3];
        floatx4 aA = {bsv.x, bsv.y, bsv.z, bsv.w};
        aA = __builtin_amdgcn_mfma_f32_16x16x16f16(wA[0], bp[0], aA, 0, 0, 0);
        floatx4 aA2 = __builtin_amdgcn_mfma_f32_16x16x16f16(wA[2], bp[2], zero4, 0, 0, 0);
        aA = __builtin_amdgcn_mfma_f32_16x16x16f16(wA[1], bp[1], aA, 0, 0, 0);
        aA2 = __builtin_amdgcn_mfma_f32_16x16x16f16(wA[3], bp[3], aA2, 0, 0, 0);
        floatx4 aB = __builtin_amdgcn_mfma_f32_16x16x16f16(wB[0], st, zero4, 0, 0, 0);
        floatx4 aB2 = __builtin_amdgcn_mfma_f32_16x16x16f16(wB[2], __builtin_bit_cast(half4, cb), zero4, 0, 0, 0);
        aB = __builtin_amdgcn_mfma_f32_16x16x16f16(wB[1], __builtin_bit_cast(half4, ca), aB, 0, 0, 0);
        aB2 = __builtin_amdgcn_mfma_f32_16x16x16f16(wB[3], __builtin_bit_cast(half4, cc), aB2, 0, 0, 0);
        bp[0] = __builtin_bit_cast(half4, na);
        bp[1] = __builtin_bit_cast(half4, nb);
        bp[2] = __builtin_bit_cast(half4, nc);
        bp[3] = __builtin_bit_cast(half4, nd);
        if (!last) {
            uint2 u;
            u.x = pk16(fast_tanh((aA[0] + aA2[0]) + (aB[0] + aB2[0])),
                       fast_tanh((aA[1] + aA2[1]) + (aB[1] + aB2[1])));
            u.y = pk16(fast_tanh((aA[2] + aA2[2]) + (aB[2] + aB2[2])),
                       fast_tanh((aA[3] + aA2[3]) + (aB[3] + aB2[3])));
            h1buf[P][wi] = u;
            st = __builtin_bit_cast(half4, u);
        } else {
            float p = 0.f;
#pragma unroll
            for (int r = 0; r < 4; ++r) {
                const float h = fast_tanh((aA[r] + aA2[r]) + (aB[r] + aB2[r]));
                p = __builtin_fmaf(h, f4e(wfc, r), p);
            }
            p += __shfl_xor(p, 16, 64);
            p += __shfl_xor(p, 32, 64);
            if (lane < 16) red[wq][n] = p;
        }
    };

    __syncthreads();   // zero-init visible to all waves

    // interval 0: L0 computes h0(0) (reads zeroed parity-1 partners)
    if (isL0) stepL0(0);
    BAR();
    // interval 1: L0 h0(1); L1 prefetches h0(0)
    if (isL0) {
        stepL0(1);
    } else {
        bp[0] = __builtin_bit_cast(half4, h0buf[0][p0]);
        bp[1] = __builtin_bit_cast(half4, h0buf[0][p1]);
        bp[2] = __builtin_bit_cast(half4, h0buf[0][p2]);
        bp[3] = __builtin_bit_cast(half4, h0buf[0][p3]);
    }
    BAR();
    // main: interval i: L0 -> h0(i); L1 -> h1(i-2)
    for (int i = 2; i < 512; i += 2) {
        if (isL0) stepL0(i); else stepL1(i, false);
        BAR();
        if (isL0) stepL0(i + 1); else stepL1(i + 1, false);
        BAR();
    }
    // tail: interval 512 -> h1(510); interval 513 -> h1(511) + FC
    if (!isL0) stepL1(512, false);
    BAR();
    if (!isL0) stepL1(513, true);
    __syncthreads();
    if (w == 4 && lane < 16)
        out[b0 + lane] = red[0][lane] + red[1][lane] + red[2][lane] + red[3][lane] + b_fc[0];
}

extern "C" void kernel_launch(void* const* d_in, const int* in_sizes, int n_in,
                              void* d_out, int out_size, void* d_ws, size_t ws_size,
                              hipStream_t stream) {
    const float* x     = (const float*)d_in[0];
    const float* W_ih0 = (const float*)d_in[1];
    const float* W_hh0 = (const float*)d_in[2];
    const float* b_ih0 = (const float*)d_in[3];
    const float* b_hh0 = (const float*)d_in[4];
    const float* W_ih1 = (const float*)d_in[5];
    const float* W_hh1 = (const float*)d_in[6];
    const float* b_ih1 = (const float*)d_in[7];
    const float* b_hh1 = (const float*)d_in[8];
    const float* W_fc  = (const float*)d_in[9];
    const float* b_fc  = (const float*)d_in[10];
    float* out = (float*)d_out;

    rnn2_r5<<<128, 512, 0, stream>>>(x, W_ih0, W_hh0, b_ih0, b_hh0,
                                     W_ih1, W_hh1, b_ih1, b_hh1,
                                     W_fc, b_fc, out);
}

// Round 6
// 284.764 us; speedup vs baseline: 1.1195x; 1.1195x over previous
//
#include <hip/hip_runtime.h>

#define TT 512

typedef _Float16 half8 __attribute__((ext_vector_type(8)));
typedef __attribute__((ext_vector_type(4))) float floatx4;

// raw workgroup barrier (no vmcnt/lgkmcnt drain); LDS FIFO is in-order per CU,
// validated R6-R12 (reads issued pre-barrier stay bit-exact vs post-barrier
// overwrites across 512 steps).
#define BAR() do { __asm__ volatile("" ::: "memory"); \
                   __builtin_amdgcn_s_barrier();      \
                   __asm__ volatile("" ::: "memory"); } while (0)

__device__ __forceinline__ float fast_tanh(float z) {
    const float e = __expf(2.f * z);
    return 1.f - __fdividef(2.f, e + 1.f);
}
__device__ __forceinline__ float f4e(const float4& v, int r) {
    return (r == 0) ? v.x : (r == 1) ? v.y : (r == 2) ? v.z : v.w;
}
__device__ __forceinline__ unsigned pk16(float a, float b) {
    const unsigned ua = __builtin_bit_cast(unsigned short, (_Float16)a);
    const unsigned ub = __builtin_bit_cast(unsigned short, (_Float16)b);
    return ua | (ub << 16);
}

// R6 = R10 champion (223 us counter-level) + T5 s_setprio graft.
// Lag-2 layer pipeline, 128 blocks x 8 waves (2/SIMD): waves 0-3 compute h0(i);
// waves 4-7 compute h1(i-2) from prefetched registers. One raw barrier per
// interval; h0/h1 double-buffered by parity. Arithmetic bit-identical to R10
// (absmax 4.882812e-4). setprio(1) wraps each wave's dependency-critical
// LDS-read + MFMA cluster: with two role-split waves per SIMD (L0 vs L1), the
// CU scheduler can prefer the wave on its critical chain (T5 mechanism;
// measured +4-7% on role-split attn, 0% on lockstep GEMM - R10 is role-split).
__global__ void __launch_bounds__(512, 1)
rnn2_prio(const float* __restrict__ x,
          const float* __restrict__ W_ih0, const float* __restrict__ W_hh0,
          const float* __restrict__ b_ih0, const float* __restrict__ b_hh0,
          const float* __restrict__ W_ih1, const float* __restrict__ W_hh1,
          const float* __restrict__ b_ih1, const float* __restrict__ b_hh1,
          const float* __restrict__ W_fc, const float* __restrict__ b_fc,
          float* __restrict__ out)
{
    __shared__ short h0f[2][1024];  // [parity][chunk*512 + 128q + 8n + j], fp16
    __shared__ short h1f[2][1024];
    __shared__ float red[4][16];

    const int tid = threadIdx.x;
    const int lane = tid & 63;
    const int w = tid >> 6;          // 0..7
    const int wq = w & 3;            // M-slice within the layer group
    const bool isL0 = (w < 4);
    const int n = lane & 15;
    const int q = lane >> 4;
    const int b0 = blockIdx.x * 16;

    // h1(-1) = 0 at parity 1 (read as c by L1 at interval 2)
    ((int*)&h1f[1][0])[tid] = 0;

    const int mrow = 16 * wq + n;
    const int m4 = 16 * wq + 4 * q;
    const int rbase = 128 * q + 8 * n;
    const int wbase = (2 * wq + (q >> 1)) * 128 + 8 * n + 4 * (q & 1);

    // ---- weight fragments, single fp16 RTNE (as R10) ----
    half8 wA[2], wB[2];  // L0: A=W_hh0 ; L1: A=W_ih1, B=W_hh1
    auto mkfrag = [&](const float* p, half8& hi) {
#pragma unroll
        for (int j = 0; j < 8; ++j) hi[j] = (_Float16)p[j];
    };
    float4 wih0v = {0, 0, 0, 0}, bv0 = {0, 0, 0, 0}, bv1 = {0, 0, 0, 0}, wfcv = {0, 0, 0, 0};
    if (isL0) {
#pragma unroll
        for (int k = 0; k < 2; ++k) mkfrag(W_hh0 + mrow * 64 + 32 * k + 8 * q, wA[k]);
        wih0v = *(const float4*)(W_ih0 + m4);
        bv0 = *(const float4*)(b_ih0 + m4);
        { float4 t = *(const float4*)(b_hh0 + m4); bv0.x += t.x; bv0.y += t.y; bv0.z += t.z; bv0.w += t.w; }
    } else {
#pragma unroll
        for (int k = 0; k < 2; ++k) {
            mkfrag(W_ih1 + mrow * 64 + 32 * k + 8 * q, wA[k]);
            mkfrag(W_hh1 + mrow * 64 + 32 * k + 8 * q, wB[k]);
        }
        bv1 = *(const float4*)(b_ih1 + m4);
        { float4 t = *(const float4*)(b_hh1 + m4); bv1.x += t.x; bv1.y += t.y; bv1.z += t.z; bv1.w += t.w; }
        wfcv = *(const float4*)(W_fc + m4);
    }

    const float* xp = x + (long)(b0 + n) * TT;
    const floatx4 zero4 = {0.f, 0.f, 0.f, 0.f};

    auto epi_write = [&](const floatx4& A, const floatx4& B, short* pf) {
        float h[4];
#pragma unroll
        for (int r = 0; r < 4; ++r) h[r] = fast_tanh(A[r] + B[r]);
        uint2 u;
        u.x = pk16(h[0], h[1]);
        u.y = pk16(h[2], h[3]);
        *(uint2*)&pf[wbase] = u;
    };

    // L0 interval: read h0[rp] (exposed, issued first), compute h0, write h0[wp]
    auto stepL0 = [&](int rp, int wp, float xvv) {
        __builtin_amdgcn_s_setprio(1);
        half8 b0v = *(const half8*)&h0f[rp][rbase];
        half8 b1v = *(const half8*)&h0f[rp][rbase + 512];
        floatx4 aA = {__builtin_fmaf(xvv, wih0v.x, bv0.x), __builtin_fmaf(xvv, wih0v.y, bv0.y),
                      __builtin_fmaf(xvv, wih0v.z, bv0.z), __builtin_fmaf(xvv, wih0v.w, bv0.w)};
        floatx4 aB = zero4;
        aA = __builtin_amdgcn_mfma_f32_16x16x32_f16(wA[0], b0v, aA, 0, 0, 0);
        aB = __builtin_amdgcn_mfma_f32_16x16x32_f16(wA[1], b1v, aB, 0, 0, 0);
        __builtin_amdgcn_s_setprio(0);
        epi_write(aA, aB, &h0f[wp][0]);
    };

    // L1 interval: own-recurrence read (c) first, prefetch next h0 (bn),
    // compute on PREFETCHED bp (no wait), then c (hidden), write; bp <- bn.
    auto stepL1 = [&](int rc, int rbn, int wp, half8* bp) {
        __builtin_amdgcn_s_setprio(1);
        half8 c0 = *(const half8*)&h1f[rc][rbase];
        half8 c1 = *(const half8*)&h1f[rc][rbase + 512];
        half8 nb0 = *(const half8*)&h0f[rbn][rbase];
        half8 nb1 = *(const half8*)&h0f[rbn][rbase + 512];
        floatx4 aA = {bv1.x, bv1.y, bv1.z, bv1.w};
        floatx4 aB = zero4;
        aA = __builtin_amdgcn_mfma_f32_16x16x32_f16(wA[0], bp[0], aA, 0, 0, 0);
        aA = __builtin_amdgcn_mfma_f32_16x16x32_f16(wA[1], bp[1], aA, 0, 0, 0);
        aB = __builtin_amdgcn_mfma_f32_16x16x32_f16(wB[0], c0, aB, 0, 0, 0);
        aB = __builtin_amdgcn_mfma_f32_16x16x32_f16(wB[1], c1, aB, 0, 0, 0);
        __builtin_amdgcn_s_setprio(0);
        epi_write(aA, aB, &h1f[wp][0]);
        bp[0] = nb0; bp[1] = nb1;
    };

    // ---- interval 0: L0 writes h0(0) -> parity 0 ----
    float xv = 0.f, xnext = 0.f;
    if (isL0) {
        const float xv0 = xp[0];
        float h[4];
#pragma unroll
        for (int r = 0; r < 4; ++r)
            h[r] = fast_tanh(__builtin_fmaf(xv0, f4e(wih0v, r), f4e(bv0, r)));
        uint2 u; u.x = pk16(h[0], h[1]); u.y = pk16(h[2], h[3]);
        *(uint2*)&h0f[0][wbase] = u;
        xv = xp[1];
        xnext = xp[2];
    }
    BAR();

    // ---- interval 1: L0 h0(1); L1 prefetches h0(0) ----
    half8 bp[2];
    if (isL0) {
        stepL0(0, 1, xv);
        xv = xnext; xnext = xp[3];
    } else {
        bp[0] = *(const half8*)&h0f[0][rbase];
        bp[1] = *(const half8*)&h0f[0][rbase + 512];
    }
    BAR();

    // ---- main loop: intervals i = 2..511 (pairs) ----
    // interval i: L0 computes h0(i); L1 computes h1(i-2), prefetches h0(i-1)
    for (int i = 2; i < 511; i += 2) {
        // P = 0
        if (isL0) {
            stepL0(1, 0, xv);
            xv = xnext; xnext = xp[(i + 2) & (TT - 1)];
        } else {
            stepL1(1, 1, 0, bp);
        }
        BAR();
        // P = 1
        if (isL0) {
            stepL0(0, 1, xv);
            xv = xnext; xnext = xp[(i + 3) & (TT - 1)];
        } else {
            stepL1(0, 0, 1, bp);
        }
        BAR();
    }

    // ---- tail interval 512: L1 computes h1(510), prefetches h0(511) ----
    if (!isL0) stepL1(1, 1, 0, bp);
    BAR();

    // ---- tail interval 513: L1 computes h1(511) in regs + FC dot ----
    float p = 0.f;
    if (!isL0) {
        __builtin_amdgcn_s_setprio(1);
        half8 c0 = *(const half8*)&h1f[0][rbase];        // h1(510), parity 0
        half8 c1 = *(const half8*)&h1f[0][rbase + 512];
        floatx4 aA = {bv1.x, bv1.y, bv1.z, bv1.w};
        floatx4 aB = zero4;
        aA = __builtin_amdgcn_mfma_f32_16x16x32_f16(wA[0], bp[0], aA, 0, 0, 0);  // h0(511)
        aA = __builtin_amdgcn_mfma_f32_16x16x32_f16(wA[1], bp[1], aA, 0, 0, 0);
        aB = __builtin_amdgcn_mfma_f32_16x16x32_f16(wB[0], c0, aB, 0, 0, 0);
        aB = __builtin_amdgcn_mfma_f32_16x16x32_f16(wB[1], c1, aB, 0, 0, 0);
        __builtin_amdgcn_s_setprio(0);
#pragma unroll
        for (int r = 0; r < 4; ++r) {
            const float h = fast_tanh(aA[r] + aB[r]);
            p = __builtin_fmaf(h, f4e(wfcv, r), p);
        }
        p += __shfl_xor(p, 16, 64);
        p += __shfl_xor(p, 32, 64);
        if (lane < 16) red[wq][lane] = p;
    }
    __syncthreads();
    if (w == 4 && lane < 16)
        out[b0 + lane] = red[0][lane] + red[1][lane] + red[2][lane] + red[3][lane] + b_fc[0];
}

extern "C" void kernel_launch(void* const* d_in, const int* in_sizes, int n_in,
                              void* d_out, int out_size, void* d_ws, size_t ws_size,
                              hipStream_t stream) {
    const float* x     = (const float*)d_in[0];
    const float* W_ih0 = (const float*)d_in[1];
    const float* W_hh0 = (const float*)d_in[2];
    const float* b_ih0 = (const float*)d_in[3];
    const float* b_hh0 = (const float*)d_in[4];
    const float* W_ih1 = (const float*)d_in[5];
    const float* W_hh1 = (const float*)d_in[6];
    const float* b_ih1 = (const float*)d_in[7];
    const float* b_hh1 = (const float*)d_in[8];
    const float* W_fc  = (const float*)d_in[9];
    const float* b_fc  = (const float*)d_in[10];
    float* out = (float*)d_out;

    rnn2_prio<<<128, 512, 0, stream>>>(x, W_ih0, W_hh0, b_ih0, b_hh0,
                                       W_ih1, W_hh1, b_ih1, b_hh1,
                                       W_fc, b_fc, out);
}